// Round 11
// baseline (46056.592 us; speedup 1.0000x reference)
//
#include <hip/hip_runtime.h>

#define LSEQ 2048
#define HID  512
#define NBG  8

// ws dword offsets
#define OFF_YT 0              // yT[2048][128] f32
#define OFF_H1 262144         // h1 ring u16[4 slot][8 bg][2 pl][64 k8][16 n][8 kk] = 1MB
#define OFF_H2 524288         // h2 ring, same
#define OFF_F1 786432         // u32 [8 slot][8 bg][16 ug][8 wv] = 8192 dw (epoch = t+1)
#define OFF_F2 794624         // u32 [8 slot][8 bg][32 j][4 mt] = 8192 dw
#define FLAG_DW 16384

// LDS byte offsets
#define TILE2B 0              // L2: h2 tiles [2]x32KB ; L1: h1 tiles [2]x32KB
#define TILE1B 65536          // L2: h1 tiles [2]x32KB
#define PSUMB  131072         // 4KB
#define OUTPB  135168         // 1KB
#define LWLB   136192         // 2KB
#define CSTB   138240         // c-state: L1 16KB / L2 8KB
#define LDSSZ  154624

typedef __attribute__((ext_vector_type(8))) short short8;
typedef __attribute__((ext_vector_type(4))) float f32x4;
typedef __attribute__((ext_vector_type(8))) unsigned short ushort8;

typedef __attribute__((address_space(1))) const unsigned int GU32;
typedef __attribute__((address_space(3))) unsigned int LU32;

__device__ __forceinline__ float sigm(float x){ return 1.0f/(1.0f + __expf(-x)); }
__device__ __forceinline__ float tanhf_fast(float x){
  float ax = fabsf(x);
  float e = __expf(2.0f*ax);
  float t = 1.0f - 2.0f/(e + 1.0f);
  return x < 0.0f ? -t : t;
}
__device__ __forceinline__ unsigned short f2bf(float x){
  unsigned u = __builtin_bit_cast(unsigned, x);
  u += 0x7fffu + ((u>>16)&1u);
  return (unsigned short)(u>>16);
}
__device__ __forceinline__ float bf2f(unsigned short h){
  unsigned u = ((unsigned)h)<<16;
  return __builtin_bit_cast(float, u);
}
__device__ __forceinline__ f32x4 mm(short8 a, short8 b, f32x4 c){
  return __builtin_amdgcn_mfma_f32_16x16x32_bf16(a, b, c, 0, 0, 0);
}

__device__ __forceinline__ unsigned fload(const unsigned* p){
  return __hip_atomic_load(p, __ATOMIC_RELAXED, __HIP_MEMORY_SCOPE_AGENT);
}
__device__ __forceinline__ void fstore(unsigned* p, unsigned v){
  __hip_atomic_store(p, v, __ATOMIC_RELAXED, __HIP_MEMORY_SCOPE_AGENT);
}
// blocking poll of 128 epoch words (wave7, 2 per lane)
__device__ __forceinline__ void poll_ge_block(const unsigned* base, int lane, unsigned ev){
  #pragma unroll
  for (int r = 0; r < 2; ++r){
    const unsigned* p = base + lane + r*64;
    while (fload(p) < ev) __builtin_amdgcn_s_sleep(1);
  }
}
__device__ __forceinline__ void st16cc(unsigned short* p, unsigned short v){
  asm volatile("global_store_short %0, %1, off sc0 sc1" :: "v"(p), "v"((unsigned)v) : "memory");
}
#define DRAIN()   asm volatile("s_waitcnt vmcnt(0)" ::: "memory")
#define DRAINN(n) asm volatile("s_waitcnt vmcnt(" #n ")" ::: "memory")

// pack 16 A-fragments (hi & lo bf16): wave covers 4 units x 4 gates, full K (r8-proven)
__device__ __forceinline__ void apack(const float* __restrict__ W, int u_w, int l15, int hig,
                                      short8* whi, short8* wlo){
  const int m = l15;
  const int row = (m&3)*HID + u_w + (m>>2);
  const float* wp0 = W + row*HID + hig*8;
  #pragma unroll
  for (int kt = 0; kt < 16; ++kt){
    short8 h8, l8;
    #pragma unroll
    for (int j = 0; j < 8; ++j){
      float v = wp0[kt*32 + j];
      unsigned short hb = f2bf(v);
      h8[j] = (short)hb;
      l8[j] = (short)f2bf(v - bf2f(hb));
    }
    whi[kt] = h8; wlo[kt] = l8;
  }
}

__device__ __forceinline__ f32x4 matvec(const unsigned char* tb, const short8* whi, const short8* wlo,
                                        int hig, int l15){
  f32x4 acc = (f32x4){0.f,0.f,0.f,0.f};
  #pragma unroll
  for (int kt = 0; kt < 16; ++kt){
    unsigned eb = (unsigned)((kt*4+hig)*16 + l15)*16u;
    short8 bhi = *(const short8*)(tb + eb);
    short8 blo = *(const short8*)(tb + 16384u + eb);
    acc = mm(whi[kt], bhi, acc);
    acc = mm(wlo[kt], bhi, acc);
    acc = mm(whi[kt], blo, acc);
  }
  return acc;
}

// stage one bg tile (32KB: hi+lo planes) into LDS, 512 threads, 4 chunks each
__device__ __forceinline__ void stage_tile(const unsigned short* src, unsigned char* dst, int tid){
  #pragma unroll
  for (int j = 0; j < 4; ++j){
    int c = tid + j*512;
    __builtin_amdgcn_global_load_lds((GU32*)(src + (size_t)c*8),
        (LU32*)(dst + (unsigned)(c & ~63)*16u), 16, 0, 0x11);
  }
}

// transpose y -> yT; zero h2 ring slot 3; zero flags (every launch)
__global__ void init_kernel(const float* __restrict__ y, float* __restrict__ ws){
  int idx = blockIdx.x*256 + threadIdx.x;
  if (idx < LSEQ*128){
    int t = idx >> 7, n = idx & 127;
    ws[OFF_YT + idx] = y[n*LSEQ + t];
  }
  if (idx < 65536) ((unsigned*)(ws + OFF_H2))[196608 + idx] = 0u;   // h2 slot3 = h2(-1) = 0
  if (idx < FLAG_DW) ((unsigned*)(ws + OFF_F1))[idx] = 0u;
}

__launch_bounds__(512)
__global__ void lstm_kernel(
    const float* __restrict__ yT,
    const float* __restrict__ Wih1, const float* __restrict__ Whh1,
    const float* __restrict__ bi1,  const float* __restrict__ bh1,
    const float* __restrict__ Wih2, const float* __restrict__ Whh2,
    const float* __restrict__ bi2,  const float* __restrict__ bh2,
    const float* __restrict__ Wlin, const float* __restrict__ blin,
    unsigned short* __restrict__ h1u, unsigned short* __restrict__ h2u,
    float* __restrict__ out, unsigned* __restrict__ f1d, unsigned* __restrict__ f2d)
{
  __shared__ unsigned char smem[LDSSZ];
  const int tid  = threadIdx.x;
  const int lane = tid & 63;
  const int wv   = __builtin_amdgcn_readfirstlane(tid >> 6);
  const int blk  = blockIdx.x;
  const int l15  = lane & 15, hig = lane >> 4;
  float* cstL = (float*)(smem + CSTB);

  if (blk < 16){
    // ================= layer 1: 16 blocks x 32 units; all 8 waves compute =================
    const int ug = blk, u0 = ug*32;
    const int u_w = u0 + wv*4;
    const int ul  = wv*4 + hig;
    short8 whi[16], wlo[16];
    apack(Whh1, u_w, l15, hig, whi, wlo);
    float bsum[4], wih[4];
    #pragma unroll
    for (int r = 0; r < 4; ++r){
      int row = r*HID + u0 + ul;
      bsum[r] = bi1[row] + bh1[row];
      wih[r]  = Wih1[row];
    }
    const int unit = u0 + ul, k8s = unit>>3, kks = unit&7;

    // ---- prologue: h1(0) for all bgs (zero state) ----
    #pragma unroll
    for (int bg = 0; bg < NBG; ++bg){
      float yv = yT[bg*16 + l15];
      float gi = bsum[0] + wih[0]*yv;
      float gg = bsum[2] + wih[2]*yv;
      float go = bsum[3] + wih[3]*yv;
      float cn = sigm(gi)*tanhf_fast(gg);
      cstL[(ul*16 + l15)*8 + bg] = cn;
      float hn = sigm(go)*tanhf_fast(cn);
      unsigned short hb = f2bf(hn);
      unsigned short* dst = h1u + ((size_t)(0*NBG + bg))*16384 + ((k8s*16 + l15)*8 + kks);
      st16cc(dst, hb);
      st16cc(dst + 8192, (unsigned short)f2bf(hn - bf2f(hb)));
    }
    DRAIN();
    if (lane == 0){
      #pragma unroll
      for (int bg = 0; bg < NBG; ++bg)
        fstore(f1d + ((size_t)(0*NBG + bg))*128 + ug*8 + wv, 1u);
    }
    // ---- pre-fill: deps(8), stage(8), deps(9) ----
    if (wv == 7) poll_ge_block(f1d + 0*128, lane, 1u);                 // F1(0,bg0)
    __syncthreads();
    stage_tile(h1u + ((size_t)(0*NBG + 0))*16384, smem + TILE2B, tid); // h1(0,bg0) -> buf0
    if (wv == 7) poll_ge_block(f1d + 1*128, lane, 1u);                 // F1(0,bg1)
    DRAIN();
    __syncthreads();

    #pragma clang loop unroll(disable)
    for (int i = 8; i <= 16383; ++i){
      const int t = i>>3, bg = i&7, q = i&1;
      // 1. issue stage(i+1)
      if (i+1 <= 16383){
        int t1 = (i+1)>>3, bg1 = (i+1)&7;
        stage_tile(h1u + ((size_t)((((t1+3)&3))*NBG + bg1))*16384, smem + TILE2B + (q^1)*32768, tid);
      }
      // 2. early dep loads for body i+2: F1(tj-1) ev=tj ; F2(tj-4) ev=tj-3
      const unsigned *pa0=nullptr,*pa1=nullptr,*pa2=nullptr,*pa3=nullptr;
      unsigned ev0=0,ev2=0;
      if (wv == 7 && i+2 <= 16383){
        int tj = (i+2)>>3, bgj = (i+2)&7;
        const unsigned* b1 = f1d + ((size_t)(((tj-1)&7)*NBG + bgj))*128;
        pa0 = b1 + lane; pa1 = b1 + lane + 64; ev0 = (unsigned)tj;
        if (tj >= 4){
          const unsigned* b2 = f2d + ((size_t)(((tj-4)&7)*NBG + bgj))*128;
          pa2 = b2 + lane; pa3 = b2 + lane + 64; ev2 = (unsigned)(tj-3);
        }
      }
      unsigned pv0 = pa0 ? fload(pa0) : ~0u;
      unsigned pv1 = pa1 ? fload(pa1) : ~0u;
      unsigned pv2 = pa2 ? fload(pa2) : ~0u;
      unsigned pv3 = pa3 ? fload(pa3) : ~0u;
      // 3. compute + act
      float yv = yT[t*128 + bg*16 + l15];
      f32x4 acc = matvec(smem + TILE2B + q*32768, whi, wlo, hig, l15);
      {
        float gi = acc[0] + bsum[0] + wih[0]*yv;
        float gf = acc[1] + bsum[1] + wih[1]*yv;
        float gg = acc[2] + bsum[2] + wih[2]*yv;
        float go = acc[3] + bsum[3] + wih[3]*yv;
        float* cp = cstL + ((ul*16 + l15)*8 + bg);
        float cn = sigm(gf)*(*cp) + sigm(gi)*tanhf_fast(gg);
        *cp = cn;
        float hn = sigm(go)*tanhf_fast(cn);
        unsigned short hb = f2bf(hn);
        unsigned short* dst = h1u + ((size_t)((t&3)*NBG + bg))*16384 + ((k8s*16 + l15)*8 + kks);
        st16cc(dst, hb);
        st16cc(dst + 8192, (unsigned short)f2bf(hn - bf2f(hb)));
      }
      // 4. finish dep polls
      if (pa0){ while (pv0 < ev0){ __builtin_amdgcn_s_sleep(1); pv0 = fload(pa0); } }
      if (pa1){ while (pv1 < ev0){ __builtin_amdgcn_s_sleep(1); pv1 = fload(pa1); } }
      if (pa2){ while (pv2 < ev2){ __builtin_amdgcn_s_sleep(1); pv2 = fload(pa2); } }
      if (pa3){ while (pv3 < ev2){ __builtin_amdgcn_s_sleep(1); pv3 = fload(pa3); } }
      // 5. drain (stage done; own 2 newest stores may remain) + lagged publish of (i-1)
      DRAINN(2);
      if (lane == 0){
        int ip = i-1, tp = ip>>3, bp = ip&7;
        fstore(f1d + ((size_t)((tp&7)*NBG + bp))*128 + ug*8 + wv, (unsigned)(tp+1));
      }
      __syncthreads();
    }
    // tail: publish body 16383
    DRAIN();
    if (lane == 0) fstore(f1d + ((size_t)((2047&7)*NBG + 7))*128 + ug*8 + wv, 2048u);

  } else {
    // ================= layer 2 (+fused out on j0): 32 blocks x 16 units =================
    const int j32 = blk - 16, u0 = j32*16;
    const int g  = wv >> 2;          // 0 = hh2 (+act), 1 = ih2 (+psum, +out on j0)
    const int mt = wv & 3;
    const int u_w = u0 + mt*4;
    const int ul  = mt*4 + hig;
    short8 whi[16], wlo[16];
    apack(g == 0 ? Whh2 : Wih2, u_w, l15, hig, whi, wlo);
    float bsum[4];
    #pragma unroll
    for (int r = 0; r < 4; ++r) bsum[r] = bi2[r*HID + u0 + ul] + bh2[r*HID + u0 + ul];
    const int unit = u0 + ul, k8s = unit>>3, kks = unit&7;
    const float bl = blin[0];
    float* lwl  = (float*)(smem + LWLB);
    float* outp = (float*)(smem + OUTPB);
    const int lastBody = (j32 == 0) ? (16384 + NBG - 1) : 16383;

    // pre-loop: zero cst, load Wlin, deps(0), stage(0), deps(1)
    #pragma unroll
    for (int r = 0; r < 4; ++r) cstL[tid + r*512] = 0.f;   // 2048 floats
    if (j32 == 0) lwl[tid] = Wlin[tid];
    if (wv == 7) poll_ge_block(f1d + 0*128, lane, 1u);      // F1(0,bg0); F2(-1) none
    __syncthreads();
    stage_tile(h2u + ((size_t)(3*NBG + 0))*16384, smem + TILE2B, tid);  // h2(-1,bg0)=0
    stage_tile(h1u + ((size_t)(0*NBG + 0))*16384, smem + TILE1B, tid);  // h1(0,bg0)
    if (wv == 7) poll_ge_block(f1d + 1*128, lane, 1u);      // deps(1): F1(0,bg1)
    DRAIN();
    __syncthreads();

    #pragma clang loop unroll(disable)
    for (int i = 0; i <= lastBody; ++i){
      const int t = i>>3, bg = i&7, q = i&1;
      const bool main_ = (i < 16384);
      // 1. issue stage(i+1)
      if (i+1 <= lastBody){
        int t1 = (i+1)>>3, bg1 = (i+1)&7;
        stage_tile(h2u + ((size_t)(((t1+3)&3)*NBG + bg1))*16384, smem + TILE2B + (q^1)*32768, tid);
        if (t1 <= 2047)
          stage_tile(h1u + ((size_t)((t1&3)*NBG + bg1))*16384, smem + TILE1B + (q^1)*32768, tid);
      }
      // 2. early dep loads for body i+2: F2(tj-1) ev=tj ; F1(tj) ev=tj+1
      const unsigned *pa0=nullptr,*pa1=nullptr,*pa2=nullptr,*pa3=nullptr;
      unsigned ev0=0,ev2=0;
      if (wv == 7 && i+2 <= lastBody){
        int tj = (i+2)>>3, bgj = (i+2)&7;
        if (tj >= 1){
          const unsigned* b2 = f2d + ((size_t)(((tj-1)&7)*NBG + bgj))*128;
          pa0 = b2 + lane; pa1 = b2 + lane + 64; ev0 = (unsigned)tj;
        }
        if (tj <= 2047){
          const unsigned* b1 = f1d + ((size_t)((tj&7)*NBG + bgj))*128;
          pa2 = b1 + lane; pa3 = b1 + lane + 64; ev2 = (unsigned)(tj+1);
        }
      }
      unsigned pv0 = pa0 ? fload(pa0) : ~0u;
      unsigned pv1 = pa1 ? fload(pa1) : ~0u;
      unsigned pv2 = pa2 ? fload(pa2) : ~0u;
      unsigned pv3 = pa3 ? fload(pa3) : ~0u;
      // 3. compute
      f32x4 acc = (f32x4){0.f,0.f,0.f,0.f};
      if (main_){
        acc = matvec(smem + (g == 0 ? TILE2B : TILE1B) + q*32768, whi, wlo, hig, l15);
        if (g == 1) *(f32x4*)(smem + PSUMB + (unsigned)(mt*64 + lane)*16u) = acc;
      }
      if (j32 == 0 && g == 1 && t >= 1){
        const unsigned char* t2 = smem + TILE2B + q*32768;   // h2(t-1,bg)
        float a = 0.f;
        #pragma unroll
        for (int k8r = 0; k8r < 4; ++k8r){
          int k8 = mt*16 + hig*4 + k8r;
          unsigned eb = (unsigned)(k8*16 + l15)*16u;
          ushort8 h8 = *(const ushort8*)(t2 + eb);
          ushort8 l8 = *(const ushort8*)(t2 + 16384u + eb);
          #pragma unroll
          for (int kk = 0; kk < 8; ++kk)
            a += (bf2f(h8[kk]) + bf2f(l8[kk])) * lwl[k8*8 + kk];
        }
        outp[(mt*4 + hig)*16 + l15] = a;
      }
      // 4. finish dep polls
      if (pa0){ while (pv0 < ev0){ __builtin_amdgcn_s_sleep(1); pv0 = fload(pa0); } }
      if (pa1){ while (pv1 < ev0){ __builtin_amdgcn_s_sleep(1); pv1 = fload(pa1); } }
      if (pa2){ while (pv2 < ev2){ __builtin_amdgcn_s_sleep(1); pv2 = fload(pa2); } }
      if (pa3){ while (pv3 < ev2){ __builtin_amdgcn_s_sleep(1); pv3 = fload(pa3); } }
      __syncthreads();                                       // B1: psum/outp ready
      // 5. act (g0) + out (j0 wv4)
      if (main_ && g == 0){
        f32x4 ps = *(const f32x4*)(smem + PSUMB + (unsigned)(mt*64 + lane)*16u);
        float gi = acc[0] + ps[0] + bsum[0];
        float gf = acc[1] + ps[1] + bsum[1];
        float gg = acc[2] + ps[2] + bsum[2];
        float go = acc[3] + ps[3] + bsum[3];
        float* cp = cstL + ((ul*16 + l15)*8 + bg);
        float cn = sigm(gf)*(*cp) + sigm(gi)*tanhf_fast(gg);
        *cp = cn;
        float hn = sigm(go)*tanhf_fast(cn);
        unsigned short hb = f2bf(hn);
        unsigned short* dst = h2u + ((size_t)((t&3)*NBG + bg))*16384 + ((k8s*16 + l15)*8 + kks);
        st16cc(dst, hb);
        st16cc(dst + 8192, (unsigned short)f2bf(hn - bf2f(hb)));
      }
      if (j32 == 0 && wv == 4 && t >= 1 && lane < 16){
        float s = bl;
        #pragma unroll
        for (int r2 = 0; r2 < 16; ++r2) s += outp[r2*16 + lane];
        out[((size_t)(bg*16 + lane))*LSEQ + (t-1)] = s;
      }
      // 6. drains + lagged publish of (i-1)
      if (!main_) { DRAIN(); }
      else if (g == 0) { DRAINN(2); }
      else { DRAINN(0); }
      if (g == 0 && i >= 1 && (i-1) <= 16383 && lane == 0){
        int ip = i-1, tp = ip>>3, bp = ip&7;
        fstore(f2d + ((size_t)((tp&7)*NBG + bp))*128 + j32*4 + mt, (unsigned)(tp+1));
      }
      __syncthreads();                                       // B2
    }
    // tail: publish body 16383 (non-j0; j0 published it at i=16384)
    if (j32 != 0 && g == 0){
      DRAIN();
      if (lane == 0) fstore(f2d + ((size_t)((2047&7)*NBG + 7))*128 + j32*4 + mt, 2048u);
    }
  }
}

extern "C" void kernel_launch(void* const* d_in, const int* in_sizes, int n_in,
                              void* d_out, int out_size, void* d_ws, size_t ws_size,
                              hipStream_t stream){
  (void)in_sizes; (void)n_in; (void)out_size; (void)ws_size;
  const float* y    = (const float*)d_in[0];
  const float* Wih1 = (const float*)d_in[1];
  const float* Whh1 = (const float*)d_in[2];
  const float* bi1  = (const float*)d_in[3];
  const float* bh1  = (const float*)d_in[4];
  const float* Wih2 = (const float*)d_in[5];
  const float* Whh2 = (const float*)d_in[6];
  const float* bi2  = (const float*)d_in[7];
  const float* bh2  = (const float*)d_in[8];
  const float* Wlin = (const float*)d_in[9];
  const float* blin = (const float*)d_in[10];
  float* ws  = (float*)d_ws;
  float* out = (float*)d_out;

  hipLaunchKernelGGL(init_kernel, dim3(1024), dim3(256), 0, stream, y, ws);

  const float* yT = ws + OFF_YT;
  unsigned short* h1u = (unsigned short*)(ws + OFF_H1);
  unsigned short* h2u = (unsigned short*)(ws + OFF_H2);
  unsigned* f1d = (unsigned*)(ws + OFF_F1);
  unsigned* f2d = (unsigned*)(ws + OFF_F2);

  void* args[] = { (void*)&yT, (void*)&Wih1, (void*)&Whh1, (void*)&bi1, (void*)&bh1,
                   (void*)&Wih2, (void*)&Whh2, (void*)&bi2, (void*)&bh2,
                   (void*)&Wlin, (void*)&blin, (void*)&h1u, (void*)&h2u,
                   (void*)&out, (void*)&f1d, (void*)&f2d };
  hipLaunchCooperativeKernel((void*)lstm_kernel, dim3(48), dim3(512), args, 0, stream);
}

// Round 12
// 27913.641 us; speedup vs baseline: 1.6500x; 1.6500x over previous
//
#include <hip/hip_runtime.h>

#define LSEQ 2048
#define HID  512
#define NBGS 8
#define NBODY 8192

// ws dword offsets
#define OFF_YT 0            // yT[2048][128] f32
#define OFF_H1 262144       // h1 ring u16[4 slot][8 bg][2 pl][64 k8][16 n][8 kk] = 1MB
#define OFF_H2 524288       // h2 ring, same
#define OFF_F1 786432       // u32 [8 bg][16 ug]   epoch = t+1
#define OFF_F2 786560       // u32 [8 bg][32 j]    epoch = t+1

// LDS byte offsets
#define PSUMB 131072        // 4KB
#define BNCB  135168        // 2KB
#define OUTPB 137216        // 1KB
#define LWLB  138240        // 2KB
#define CSTB  140288        // 8KB (L1) / 4KB (L2)
#define LDSSZ 148480

typedef __attribute__((ext_vector_type(8))) short short8;
typedef __attribute__((ext_vector_type(4))) float f32x4;
typedef __attribute__((ext_vector_type(8))) unsigned short ushort8;

typedef __attribute__((address_space(1))) const unsigned int GU32;
typedef __attribute__((address_space(3))) unsigned int LU32;

__device__ __forceinline__ float sigm(float x){ return 1.0f/(1.0f + __expf(-x)); }
__device__ __forceinline__ float tanhf_fast(float x){
  float ax = fabsf(x);
  float e = __expf(2.0f*ax);
  float t = 1.0f - 2.0f/(e + 1.0f);
  return x < 0.0f ? -t : t;
}
__device__ __forceinline__ unsigned short f2bf(float x){
  unsigned u = __builtin_bit_cast(unsigned, x);
  u += 0x7fffu + ((u>>16)&1u);
  return (unsigned short)(u>>16);
}
__device__ __forceinline__ float bf2f(unsigned short h){
  unsigned u = ((unsigned)h)<<16;
  return __builtin_bit_cast(float, u);
}
__device__ __forceinline__ f32x4 mm(short8 a, short8 b, f32x4 c){
  return __builtin_amdgcn_mfma_f32_16x16x32_bf16(a, b, c, 0, 0, 0);
}

__device__ __forceinline__ unsigned fload(const unsigned* p){
  return __hip_atomic_load(p, __ATOMIC_RELAXED, __HIP_MEMORY_SCOPE_AGENT);
}
__device__ __forceinline__ void fstore(unsigned* p, unsigned v){
  __hip_atomic_store(p, v, __ATOMIC_RELAXED, __HIP_MEMORY_SCOPE_AGENT);
}
__device__ __forceinline__ void st128cc(unsigned short* p, ushort8 v){
  asm volatile("global_store_dwordx4 %0, %1, off sc0 sc1" :: "v"(p), "v"(v) : "memory");
}

#define SBAR0() __builtin_amdgcn_sched_barrier(0)
#define BAR()   do{ SBAR0(); __builtin_amdgcn_s_barrier(); SBAR0(); }while(0)
#define WAITV8() do{ asm volatile("s_waitcnt vmcnt(8)" ::: "memory"); SBAR0(); }while(0)
#define WAITV4() do{ asm volatile("s_waitcnt vmcnt(4)" ::: "memory"); SBAR0(); }while(0)
#define WAITV0() do{ asm volatile("s_waitcnt vmcnt(0)" ::: "memory"); SBAR0(); }while(0)
#define WAITL0() do{ asm volatile("s_waitcnt lgkmcnt(0)" ::: "memory"); SBAR0(); }while(0)

// pack 16 A-fragments (hi & lo bf16): wave covers 4 units x 4 gates, full K (r8-proven)
__device__ __forceinline__ void apack(const float* __restrict__ W, int u_w, int l15, int hig,
                                      short8* whi, short8* wlo){
  const int m = l15;
  const int row = (m&3)*HID + u_w + (m>>2);
  const float* wp0 = W + row*HID + hig*8;
  #pragma unroll
  for (int kt = 0; kt < 16; ++kt){
    short8 h8, l8;
    #pragma unroll
    for (int j = 0; j < 8; ++j){
      float v = wp0[kt*32 + j];
      unsigned short hb = f2bf(v);
      h8[j] = (short)hb;
      l8[j] = (short)f2bf(v - bf2f(hb));
    }
    whi[kt] = h8; wlo[kt] = l8;
  }
}

// matvec on a 16KB-plane tile (N=16): 48 MFMA
__device__ __forceinline__ f32x4 matvec(const unsigned char* tb, const short8* whi, const short8* wlo,
                                        int hig, int l15){
  f32x4 acc = (f32x4){0.f,0.f,0.f,0.f};
  #pragma unroll
  for (int kt = 0; kt < 16; ++kt){
    unsigned eb = (unsigned)((kt*4+hig)*16 + l15)*16u;
    short8 bhi = *(const short8*)(tb + eb);
    short8 blo = *(const short8*)(tb + 16384u + eb);
    acc = mm(whi[kt], bhi, acc);
    acc = mm(wlo[kt], bhi, acc);
    acc = mm(whi[kt], blo, acc);
  }
  return acc;
}

// pollster: lanes 0-15 watch F1 words, lanes 16-47 watch F2 words
__device__ __forceinline__ void poll_deps(const unsigned* F1b, const unsigned* F2b, int lane,
                                          unsigned tgt1, unsigned tgt2){
  const unsigned* p = (lane < 16) ? (F1b + lane) : ((lane < 48) ? (F2b + lane - 16) : F1b);
  unsigned tgt = (lane < 16) ? tgt1 : ((lane < 48) ? tgt2 : 0u);
  while (true){
    unsigned v = fload(p);
    if (__ballot(v < tgt) == 0ull) break;
    __builtin_amdgcn_s_sleep(2);
  }
}

// transpose y -> yT; zero h2 ring slot 3; zero flags (every launch)
__global__ void init_kernel(const float* __restrict__ y, float* __restrict__ ws){
  int idx = blockIdx.x*256 + threadIdx.x;
  if (idx < LSEQ*128){
    int t = idx >> 7, n = idx & 127;
    ws[OFF_YT + idx] = y[n*LSEQ + t];
  }
  if (idx < 65536) ((unsigned*)(ws + OFF_H2))[196608 + idx] = 0u;   // h2 slot3 = h2(-1) = 0
  if (idx < 384) ((unsigned*)(ws + OFF_F1))[idx] = 0u;
}

__launch_bounds__(576)
__global__ void lstm_kernel(
    const float* __restrict__ yT,
    const float* __restrict__ Wih1, const float* __restrict__ Whh1,
    const float* __restrict__ bi1,  const float* __restrict__ bh1,
    const float* __restrict__ Wih2, const float* __restrict__ Whh2,
    const float* __restrict__ bi2,  const float* __restrict__ bh2,
    const float* __restrict__ Wlin, const float* __restrict__ blin,
    unsigned short* __restrict__ h1u, unsigned short* __restrict__ h2u,
    float* __restrict__ out, unsigned* __restrict__ f1d, unsigned* __restrict__ f2d)
{
  __shared__ unsigned char smem[LDSSZ];
  unsigned short* bnc = (unsigned short*)(smem + BNCB);
  float* cst = (float*)(smem + CSTB);
  const int tid  = threadIdx.x;
  const int lane = tid & 63;
  const int wv   = __builtin_amdgcn_readfirstlane(tid >> 6);
  const int blk  = blockIdx.x;
  const int l15  = lane & 15, hig = lane >> 4;
  const bool wrk = (wv < 8);

  if (blk < 32){
    // ========== layer 1: 2 quads x 16 blocks, 32 units/block, 8 worker waves + pollster ==========
    const int qb = blk >> 4, ug = blk & 15;
    const int u0 = ug*32;
    const unsigned* F1q = f1d;            // full arrays; bg indexed
    short8 whi[16], wlo[16];
    float bsum[4], wih[4];
    const int ul = wv*4 + hig;            // local unit (workers)
    if (wrk){
      apack(Whh1, u0 + wv*4, l15, hig, whi, wlo);
      #pragma unroll
      for (int r = 0; r < 4; ++r){
        int row = r*HID + u0 + ul;
        bsum[r] = bi1[row] + bh1[row];
        wih[r]  = Wih1[row];
      }
    }
    const int unit = u0 + ul, k8l = (ul>>3), kk = ul&7;

    // ---- prologue: h1(0) for 4 bgs ----
    for (int b = 0; b < 4; ++b){
      const int bg = qb*4 + b;
      if (wrk){
        float yv = yT[bg*16 + l15];
        float gi = bsum[0] + wih[0]*yv;
        float gg = bsum[2] + wih[2]*yv;
        float go = bsum[3] + wih[3]*yv;
        float cn = sigm(gi)*tanhf_fast(gg);
        cst[(ul*16 + l15)*4 + b] = cn;
        float hn = sigm(go)*tanhf_fast(cn);
        unsigned short hb = f2bf(hn);
        bnc[(k8l*16 + l15)*8 + kk]       = hb;
        bnc[512 + (k8l*16 + l15)*8 + kk] = f2bf(hn - bf2f(hb));
      }
      WAITL0(); BAR();
      if (wv == 0){
        unsigned short* sb = h1u + ((size_t)(0*NBGS + bg))*16384;
        #pragma unroll
        for (int q = 0; q < 2; ++q){
          int pc = lane + q*64;
          int pl = pc>>6, idx = pc&63, kb = idx>>4, n = idx&15;
          ushort8 v = *(const ushort8*)(bnc + pl*512 + idx*8);
          st128cc(sb + pl*8192 + ((ug*4 + kb)*16 + n)*8, v);
        }
      }
      BAR();
    }
    if (wv == 0){
      WAITV0();
      if (lane == 0){
        #pragma unroll
        for (int b = 0; b < 4; ++b) fstore(f1d + (qb*4+b)*16 + ug, 1u);
      }
    }
    // ---- warmup: deps(4), stage(4), deps(5) ----
    if (wv == 8) poll_deps(f1d + (qb*4+0)*16, f2d + (qb*4+0)*32, lane, 1u, 0u);  // body4: t=1,b=0
    BAR();
    if (wrk){
      const unsigned short* s1 = h1u + ((size_t)(0*NBGS + qb*4))*16384;  // h1(0,bg0), slot 0
      #pragma unroll
      for (int j = 0; j < 4; ++j){
        int c = wv*4 + j;
        __builtin_amdgcn_global_load_lds((GU32*)(s1 + (size_t)(c*64 + lane)*8),
                                         (LU32*)(smem + c*1024), 16, 0, 0x11);
      }
    }
    if (wv == 8) poll_deps(f1d + (qb*4+1)*16, f2d + (qb*4+1)*32, lane, 1u, 0u);  // body5
    BAR();

    // ---- main loop: bodies 4..8191 ----
    #pragma clang loop unroll(disable)
    for (int i = 4; i < NBODY; ++i){
      const int t = i>>2, b = i&3, bg = qb*4 + b;
      float yv = 0.f;
      if (wrk){
        // stores for body i-1 (bounce filled last body)
        if (wv == 0 && i > 4){
          int ip = i-1, tp = ip>>2, bp = qb*4 + (ip&3);
          unsigned short* sb = h1u + ((size_t)((tp&3)*NBGS + bp))*16384;
          #pragma unroll
          for (int q = 0; q < 2; ++q){
            int pc = lane + q*64;
            int pl = pc>>6, idx = pc&63, kb = idx>>4, n = idx&15;
            ushort8 v = *(const ushort8*)(bnc + pl*512 + idx*8);
            st128cc(sb + pl*8192 + ((ug*4 + kb)*16 + n)*8, v);
          }
        }
        yv = yT[t*128 + bg*16 + l15];
        // stage body i+1: h1(t1-1, bg1)
        if (i+1 < NBODY){
          int t1 = (i+1)>>2, bg1 = qb*4 + ((i+1)&3);
          const unsigned short* s1 = h1u + ((size_t)((((t1-1)&3))*NBGS + bg1))*16384;
          unsigned char* d = smem + ((i+1)&1)*32768;
          #pragma unroll
          for (int j = 0; j < 4; ++j){
            int c = wv*4 + j;
            __builtin_amdgcn_global_load_lds((GU32*)(s1 + (size_t)(c*64 + lane)*8),
                                             (LU32*)(d + c*1024), 16, 0, 0x11);
          }
          WAITV4();
        } else {
          WAITV0();
        }
        if (wv == 0 && i > 4 && lane == 0){
          int ip = i-1, tp = ip>>2, bp = qb*4 + (ip&3);
          fstore(f1d + bp*16 + ug, (unsigned)(tp+1));
        }
      }
      BAR();                                          // B_e: tile(i) ready
      if (wrk){
        f32x4 acc = matvec(smem + (i&1)*32768, whi, wlo, hig, l15);
        float gi = acc[0] + bsum[0] + wih[0]*yv;
        float gf = acc[1] + bsum[1] + wih[1]*yv;
        float gg = acc[2] + bsum[2] + wih[2]*yv;
        float go = acc[3] + bsum[3] + wih[3]*yv;
        float* cp = cst + ((ul*16 + l15)*4 + b);
        float cn = sigm(gf)*(*cp) + sigm(gi)*tanhf_fast(gg);
        *cp = cn;
        float hn = sigm(go)*tanhf_fast(cn);
        unsigned short hb = f2bf(hn);
        bnc[(k8l*16 + l15)*8 + kk]       = hb;
        bnc[512 + (k8l*16 + l15)*8 + kk] = f2bf(hn - bf2f(hb));
        WAITL0();
      } else {
        if (i+2 < NBODY){
          int tj = (i+2)>>2, bgj = qb*4 + ((i+2)&3);
          poll_deps(f1d + bgj*16, f2d + bgj*32, lane,
                    (unsigned)tj, (tj>=4)?(unsigned)(tj-3):0u);
        }
      }
      BAR();                                          // B_bounce
    }
    // tail: store + publish body 8191
    if (wv == 0){
      unsigned short* sb = h1u + ((size_t)((2047&3)*NBGS + (qb*4+3)))*16384;
      #pragma unroll
      for (int q = 0; q < 2; ++q){
        int pc = lane + q*64;
        int pl = pc>>6, idx = pc&63, kb = idx>>4, n = idx&15;
        ushort8 v = *(const ushort8*)(bnc + pl*512 + idx*8);
        st128cc(sb + pl*8192 + ((ug*4 + kb)*16 + n)*8, v);
      }
      WAITV0();
      if (lane == 0) fstore(f1d + (qb*4+3)*16 + ug, 2048u);
    }
  } else {
    // ========== layer 2 (+fused out on j0): 2 quads x 32 blocks, 16 units ==========
    const int b2 = blk - 32, qb = b2 >> 5, j32 = b2 & 31;
    const int u0 = j32*16;
    const int g  = wv >> 2;          // workers: 0 = hh2(+act), 1 = ih2(+psum,+out on j0)
    const int mt = wv & 3;
    const int ul = mt*4 + hig;
    short8 whi[16], wlo[16];
    float bsum[4];
    if (wrk){
      apack((g==0) ? Whh2 : Wih2, u0 + mt*4, l15, hig, whi, wlo);
      #pragma unroll
      for (int r = 0; r < 4; ++r) bsum[r] = bi2[r*HID + u0 + ul] + bh2[r*HID + u0 + ul];
    }
    const int k8l = ul>>3, kk = ul&7;
    const float bl = blin[0];
    float* lwl  = (float*)(smem + LWLB);
    float* outp = (float*)(smem + OUTPB);

    // pre-loop: zero cst (1024 f), load Wlin (j0)
    for (int r = tid; r < 1024; r += 576) cst[r] = 0.f;
    if (j32 == 0 && tid < 512) lwl[tid] = Wlin[tid];
    // warmup: deps(0), stage(0), deps(1)
    if (wv == 8) poll_deps(f1d + (qb*4+0)*16, f2d + (qb*4+0)*32, lane, 1u, 0u);  // body0: t=0
    WAITL0(); BAR();
    if (wrk){
      const unsigned short* s2 = h2u + ((size_t)(3*NBGS + qb*4))*16384;   // h2(-1,bg0)
      const unsigned short* s1 = h1u + ((size_t)(0*NBGS + qb*4))*16384;   // h1(0,bg0)
      #pragma unroll
      for (int j = 0; j < 4; ++j){
        int c = wv*4 + j;
        __builtin_amdgcn_global_load_lds((GU32*)(s2 + (size_t)(c*64 + lane)*8),
                                         (LU32*)(smem + c*1024), 16, 0, 0x11);
        __builtin_amdgcn_global_load_lds((GU32*)(s1 + (size_t)(c*64 + lane)*8),
                                         (LU32*)(smem + 32768 + c*1024), 16, 0, 0x11);
      }
    }
    if (wv == 8) poll_deps(f1d + (qb*4+1)*16, f2d + (qb*4+1)*32, lane, 1u, 0u);  // body1
    BAR();

    // ---- main loop: bodies 0..8191 ----
    #pragma clang loop unroll(disable)
    for (int i = 0; i < NBODY; ++i){
      const int t = i>>2, b = i&3, bg = qb*4 + b;
      if (wrk){
        if (wv == 0 && i > 0){
          int ip = i-1, tp = ip>>2, bp = qb*4 + (ip&3);
          unsigned short* sb = h2u + ((size_t)((tp&3)*NBGS + bp))*16384;
          int pl = lane>>5, idx = lane&31, kb = idx>>4, n = idx&15;
          ushort8 v = *(const ushort8*)(bnc + pl*256 + idx*8);
          st128cc(sb + pl*8192 + ((j32*2 + kb)*16 + n)*8, v);
        }
        if (i+1 < NBODY){
          int t1 = (i+1)>>2, bg1 = qb*4 + ((i+1)&3);
          const unsigned short* s2 = h2u + ((size_t)((((t1+3)&3))*NBGS + bg1))*16384;
          const unsigned short* s1 = h1u + ((size_t)(((t1&3))*NBGS + bg1))*16384;
          unsigned char* d = smem + ((i+1)&1)*65536;
          #pragma unroll
          for (int j = 0; j < 4; ++j){
            int c = wv*4 + j;
            __builtin_amdgcn_global_load_lds((GU32*)(s2 + (size_t)(c*64 + lane)*8),
                                             (LU32*)(d + c*1024), 16, 0, 0x11);
            __builtin_amdgcn_global_load_lds((GU32*)(s1 + (size_t)(c*64 + lane)*8),
                                             (LU32*)(d + 32768 + c*1024), 16, 0, 0x11);
          }
          WAITV8();
        } else {
          WAITV0();
        }
        if (wv == 0 && i > 0 && lane == 0){
          int ip = i-1, tp = ip>>2, bp = qb*4 + (ip&3);
          fstore(f2d + bp*32 + j32, (unsigned)(tp+1));
        }
      }
      BAR();                                          // B_e
      f32x4 acc = (f32x4){0.f,0.f,0.f,0.f};
      if (wrk){
        const unsigned char* tb = smem + (i&1)*65536 + (g ? 32768 : 0);
        acc = matvec(tb, whi, wlo, hig, l15);
        if (g == 1) *(f32x4*)(smem + PSUMB + (unsigned)(mt*64 + lane)*16u) = acc;
        WAITL0();
      } else {
        if (i+2 < NBODY){
          int tj = (i+2)>>2, bgj = qb*4 + ((i+2)&3);
          poll_deps(f1d + bgj*16, f2d + bgj*32, lane, (unsigned)(tj+1), (unsigned)tj);
        }
      }
      BAR();                                          // B_g: psum ready
      if (wrk){
        if (g == 0){
          f32x4 ps = *(const f32x4*)(smem + PSUMB + (unsigned)(mt*64 + lane)*16u);
          float gi = acc[0] + ps[0] + bsum[0];
          float gf = acc[1] + ps[1] + bsum[1];
          float gg = acc[2] + ps[2] + bsum[2];
          float go = acc[3] + ps[3] + bsum[3];
          float* cp = cst + ((ul*16 + l15)*4 + b);
          float cn = sigm(gf)*(*cp) + sigm(gi)*tanhf_fast(gg);
          *cp = cn;
          float hn = sigm(go)*tanhf_fast(cn);
          unsigned short hb = f2bf(hn);
          bnc[(k8l*16 + l15)*8 + kk]       = hb;
          bnc[256 + (k8l*16 + l15)*8 + kk] = f2bf(hn - bf2f(hb));
        } else if (j32 == 0 && t >= 1){
          const unsigned char* t2 = smem + (i&1)*65536;   // h2(t-1,bg) tile
          int s = mt*4 + hig;
          float a = 0.f;
          #pragma unroll
          for (int k8r = 0; k8r < 4; ++k8r){
            int k8 = s*4 + k8r;
            unsigned eb = (unsigned)(k8*16 + l15)*16u;
            ushort8 h8 = *(const ushort8*)(t2 + eb);
            ushort8 l8 = *(const ushort8*)(t2 + 16384u + eb);
            #pragma unroll
            for (int c = 0; c < 8; ++c)
              a += (bf2f(h8[c]) + bf2f(l8[c])) * lwl[k8*8 + c];
          }
          outp[s*16 + l15] = a;
        }
        WAITL0();
      }
      BAR();                                          // B_g2: bounce + outp ready
      if (wrk && wv == 4 && j32 == 0 && t >= 1 && lane < 16){
        float s = bl;
        #pragma unroll
        for (int r = 0; r < 16; ++r) s += outp[r*16 + lane];
        out[((size_t)(bg*16 + lane))*LSEQ + (t-1)] = s;
      }
    }
    // tail: store + publish body 8191
    if (wv == 0){
      unsigned short* sb = h2u + ((size_t)((2047&3)*NBGS + (qb*4+3)))*16384;
      int pl = lane>>5, idx = lane&31, kb = idx>>4, n = idx&15;
      ushort8 v = *(const ushort8*)(bnc + pl*256 + idx*8);
      st128cc(sb + pl*8192 + ((j32*2 + kb)*16 + n)*8, v);
      WAITV0();
      if (lane == 0) fstore(f2d + (qb*4+3)*32 + j32, 2048u);
    }
    // epilogue: out(2047) on j0 blocks, 4 rounds
    if (j32 == 0){
      for (int b = 0; b < 4; ++b){
        const int bg = qb*4 + b;
        if (wv == 8) poll_deps(f1d + bg*16, f2d + bg*32, lane, 0u, 2048u);
        BAR();
        if (wrk){
          const unsigned short* s2 = h2u + ((size_t)(3*NBGS + bg))*16384;  // h2(2047): slot 3
          #pragma unroll
          for (int j = 0; j < 4; ++j){
            int c = wv*4 + j;
            __builtin_amdgcn_global_load_lds((GU32*)(s2 + (size_t)(c*64 + lane)*8),
                                             (LU32*)(smem + c*1024), 16, 0, 0x11);
          }
          WAITV0();
        }
        BAR();
        if (wrk && g == 1){
          int s = mt*4 + hig;
          float a = 0.f;
          #pragma unroll
          for (int k8r = 0; k8r < 4; ++k8r){
            int k8 = s*4 + k8r;
            unsigned eb = (unsigned)(k8*16 + l15)*16u;
            ushort8 h8 = *(const ushort8*)(smem + eb);
            ushort8 l8 = *(const ushort8*)(smem + 16384u + eb);
            #pragma unroll
            for (int c = 0; c < 8; ++c)
              a += (bf2f(h8[c]) + bf2f(l8[c])) * lwl[k8*8 + c];
          }
          outp[s*16 + l15] = a;
          WAITL0();
        }
        BAR();
        if (wrk && wv == 4 && lane < 16){
          float s = bl;
          #pragma unroll
          for (int r = 0; r < 16; ++r) s += outp[r*16 + lane];
          out[((size_t)(bg*16 + lane))*LSEQ + 2047] = s;
        }
      }
    }
  }
}

extern "C" void kernel_launch(void* const* d_in, const int* in_sizes, int n_in,
                              void* d_out, int out_size, void* d_ws, size_t ws_size,
                              hipStream_t stream){
  (void)in_sizes; (void)n_in; (void)out_size; (void)ws_size;
  const float* y    = (const float*)d_in[0];
  const float* Wih1 = (const float*)d_in[1];
  const float* Whh1 = (const float*)d_in[2];
  const float* bi1  = (const float*)d_in[3];
  const float* bh1  = (const float*)d_in[4];
  const float* Wih2 = (const float*)d_in[5];
  const float* Whh2 = (const float*)d_in[6];
  const float* bi2  = (const float*)d_in[7];
  const float* bh2  = (const float*)d_in[8];
  const float* Wlin = (const float*)d_in[9];
  const float* blin = (const float*)d_in[10];
  float* ws  = (float*)d_ws;
  float* out = (float*)d_out;

  hipLaunchKernelGGL(init_kernel, dim3(1024), dim3(256), 0, stream, y, ws);

  const float* yT = ws + OFF_YT;
  unsigned short* h1u = (unsigned short*)(ws + OFF_H1);
  unsigned short* h2u = (unsigned short*)(ws + OFF_H2);
  unsigned* f1d = (unsigned*)(ws + OFF_F1);
  unsigned* f2d = (unsigned*)(ws + OFF_F2);

  void* args[] = { (void*)&yT, (void*)&Wih1, (void*)&Whh1, (void*)&bi1, (void*)&bh1,
                   (void*)&Wih2, (void*)&Whh2, (void*)&bi2, (void*)&bh2,
                   (void*)&Wlin, (void*)&blin, (void*)&h1u, (void*)&h2u,
                   (void*)&out, (void*)&f1d, (void*)&f2d };
  hipLaunchCooperativeKernel((void*)lstm_kernel, dim3(96), dim3(576), args, 0, stream);
}

// Round 13
// 24732.188 us; speedup vs baseline: 1.8622x; 1.1286x over previous
//
#include <hip/hip_runtime.h>

#define LSEQ 2048
#define HID  512
#define NBGS 8
#define NBODY 8192

// ws dword offsets
#define OFF_YT 0            // yT[2048][128] f32
#define OFF_H1 262144       // h1 ring u16[4 slot][8 bg][2 pl][64 k8][16 n][8 kk] = 1MB
#define OFF_H2 524288       // h2 ring, same
#define OFF_F1 786432       // u32 [8 bg][16 ug]   epoch = t+1 (monotone)
#define OFF_F2 786560       // u32 [8 bg][32 j]    epoch = t+1

// LDS byte offsets
#define PSUMB 131072        // 4KB
#define BNCB  135168        // 2KB
#define OUTPB 137216        // 1KB
#define LWLB  138240        // 2KB
#define CSTB  140288        // 8KB (L1) / 4KB (L2)
#define LDSSZ 148480

typedef __attribute__((ext_vector_type(8))) short short8;
typedef __attribute__((ext_vector_type(4))) float f32x4;
typedef __attribute__((ext_vector_type(8))) unsigned short ushort8;

typedef __attribute__((address_space(1))) const unsigned int GU32;
typedef __attribute__((address_space(3))) unsigned int LU32;

__device__ __forceinline__ float sigm(float x){ return 1.0f/(1.0f + __expf(-x)); }
__device__ __forceinline__ float tanhf_fast(float x){
  float ax = fabsf(x);
  float e = __expf(2.0f*ax);
  float t = 1.0f - 2.0f/(e + 1.0f);
  return x < 0.0f ? -t : t;
}
__device__ __forceinline__ unsigned short f2bf(float x){
  unsigned u = __builtin_bit_cast(unsigned, x);
  u += 0x7fffu + ((u>>16)&1u);
  return (unsigned short)(u>>16);
}
__device__ __forceinline__ float bf2f(unsigned short h){
  unsigned u = ((unsigned)h)<<16;
  return __builtin_bit_cast(float, u);
}
__device__ __forceinline__ f32x4 mm(short8 a, short8 b, f32x4 c){
  return __builtin_amdgcn_mfma_f32_16x16x32_bf16(a, b, c, 0, 0, 0);
}

__device__ __forceinline__ unsigned fload(const unsigned* p){
  return __hip_atomic_load(p, __ATOMIC_RELAXED, __HIP_MEMORY_SCOPE_AGENT);
}
__device__ __forceinline__ void fstore(unsigned* p, unsigned v){
  __hip_atomic_store(p, v, __ATOMIC_RELAXED, __HIP_MEMORY_SCOPE_AGENT);
}
__device__ __forceinline__ void st128cc(unsigned short* p, ushort8 v){
  asm volatile("global_store_dwordx4 %0, %1, off sc0 sc1" :: "v"(p), "v"(v) : "memory");
}

#define SBAR0() __builtin_amdgcn_sched_barrier(0)
#define BAR()   do{ SBAR0(); __builtin_amdgcn_s_barrier(); SBAR0(); }while(0)
#define WAITV8() do{ asm volatile("s_waitcnt vmcnt(8)" ::: "memory"); SBAR0(); }while(0)
#define WAITV4() do{ asm volatile("s_waitcnt vmcnt(4)" ::: "memory"); SBAR0(); }while(0)
#define WAITV0() do{ asm volatile("s_waitcnt vmcnt(0)" ::: "memory"); SBAR0(); }while(0)
#define WAITL0() do{ asm volatile("s_waitcnt lgkmcnt(0)" ::: "memory"); SBAR0(); }while(0)

// pack 16 A-fragments (hi & lo bf16): wave covers 4 units x 4 gates, full K (r8-proven)
__device__ __forceinline__ void apack(const float* __restrict__ W, int u_w, int l15, int hig,
                                      short8* whi, short8* wlo){
  const int m = l15;
  const int row = (m&3)*HID + u_w + (m>>2);
  const float* wp0 = W + row*HID + hig*8;
  #pragma unroll
  for (int kt = 0; kt < 16; ++kt){
    short8 h8, l8;
    #pragma unroll
    for (int j = 0; j < 8; ++j){
      float v = wp0[kt*32 + j];
      unsigned short hb = f2bf(v);
      h8[j] = (short)hb;
      l8[j] = (short)f2bf(v - bf2f(hb));
    }
    whi[kt] = h8; wlo[kt] = l8;
  }
}

// matvec on a 16KB-plane tile (N=16): 48 MFMA
__device__ __forceinline__ f32x4 matvec(const unsigned char* tb, const short8* whi, const short8* wlo,
                                        int hig, int l15){
  f32x4 acc = (f32x4){0.f,0.f,0.f,0.f};
  #pragma unroll
  for (int kt = 0; kt < 16; ++kt){
    unsigned eb = (unsigned)((kt*4+hig)*16 + l15)*16u;
    short8 bhi = *(const short8*)(tb + eb);
    short8 blo = *(const short8*)(tb + 16384u + eb);
    acc = mm(whi[kt], bhi, acc);
    acc = mm(wlo[kt], bhi, acc);
    acc = mm(whi[kt], blo, acc);
  }
  return acc;
}

// service-wave poll: lanes 0-15 watch F1 words, lanes 16-47 watch F2 words
__device__ __forceinline__ void poll_deps(const unsigned* F1b, const unsigned* F2b, int lane,
                                          unsigned tgt1, unsigned tgt2){
  const unsigned* p = (lane < 16) ? (F1b + lane) : ((lane < 48) ? (F2b + lane - 16) : F1b);
  unsigned tgt = (lane < 16) ? tgt1 : ((lane < 48) ? tgt2 : 0u);
  while (true){
    unsigned v = fload(p);
    if (__ballot(v < tgt) == 0ull) break;
    __builtin_amdgcn_s_sleep(2);
  }
}

// transpose y -> yT; zero h2 ring slot 3; zero flags (every launch)
__global__ void init_kernel(const float* __restrict__ y, float* __restrict__ ws){
  int idx = blockIdx.x*256 + threadIdx.x;
  if (idx < LSEQ*128){
    int t = idx >> 7, n = idx & 127;
    ws[OFF_YT + idx] = y[n*LSEQ + t];
  }
  if (idx < 65536) ((unsigned*)(ws + OFF_H2))[196608 + idx] = 0u;   // h2 slot3 = h2(-1) = 0
  if (idx < 384) ((unsigned*)(ws + OFF_F1))[idx] = 0u;
}

__launch_bounds__(576)
__global__ void lstm_kernel(
    const float* __restrict__ yT,
    const float* __restrict__ Wih1, const float* __restrict__ Whh1,
    const float* __restrict__ bi1,  const float* __restrict__ bh1,
    const float* __restrict__ Wih2, const float* __restrict__ Whh2,
    const float* __restrict__ bi2,  const float* __restrict__ bh2,
    const float* __restrict__ Wlin, const float* __restrict__ blin,
    unsigned short* __restrict__ h1u, unsigned short* __restrict__ h2u,
    float* __restrict__ out, unsigned* __restrict__ f1d, unsigned* __restrict__ f2d)
{
  __shared__ unsigned char smem[LDSSZ];
  unsigned short* bnc = (unsigned short*)(smem + BNCB);
  float* cst = (float*)(smem + CSTB);
  const int tid  = threadIdx.x;
  const int lane = tid & 63;
  const int wv   = __builtin_amdgcn_readfirstlane(tid >> 6);
  const int blk  = blockIdx.x;
  const int l15  = lane & 15, hig = lane >> 4;
  const bool wrk = (wv < 8);

  if (blk < 32){
    // ========== layer 1: 2 quads x 16 blocks, 32 units/block; 8 workers + service wave ==========
    const int qb = blk >> 4, ug = blk & 15;
    const int u0 = ug*32;
    short8 whi[16], wlo[16];
    float bsum[4], wih[4];
    const int ul = wv*4 + hig;            // workers' local unit
    if (wrk){
      apack(Whh1, u0 + wv*4, l15, hig, whi, wlo);
      #pragma unroll
      for (int r = 0; r < 4; ++r){
        int row = r*HID + u0 + ul;
        bsum[r] = bi1[row] + bh1[row];
        wih[r]  = Wih1[row];
      }
    }
    const int k8l = (ul>>3), kk = ul&7;

    // ---- prologue: h1(0) for 4 bgs ----
    for (int b = 0; b < 4; ++b){
      const int bg = qb*4 + b;
      if (wrk){
        float yv = yT[bg*16 + l15];
        float gi = bsum[0] + wih[0]*yv;
        float gg = bsum[2] + wih[2]*yv;
        float go = bsum[3] + wih[3]*yv;
        float cn = sigm(gi)*tanhf_fast(gg);
        cst[(ul*16 + l15)*4 + b] = cn;
        float hn = sigm(go)*tanhf_fast(cn);
        unsigned short hb = f2bf(hn);
        bnc[(k8l*16 + l15)*8 + kk]       = hb;
        bnc[512 + (k8l*16 + l15)*8 + kk] = f2bf(hn - bf2f(hb));
      }
      WAITL0(); BAR();
      if (wv == 8){
        unsigned short* sb = h1u + ((size_t)(0*NBGS + bg))*16384;
        #pragma unroll
        for (int q = 0; q < 2; ++q){
          int pc = lane + q*64;
          int pl = pc>>6, idx = pc&63, kb = idx>>4, n = idx&15;
          ushort8 v = *(const ushort8*)(bnc + pl*512 + idx*8);
          st128cc(sb + pl*8192 + ((ug*4 + kb)*16 + n)*8, v);
        }
        WAITV0();
        if (lane == 0) fstore(f1d + bg*16 + ug, 1u);
      }
      BAR();
    }
    // ---- warmup: deps(4), stage(4), deps(5) ----
    if (wv == 8) poll_deps(f1d + (qb*4+0)*16, f2d + (qb*4+0)*32, lane, 1u, 0u);
    BAR();
    if (wrk){
      const unsigned short* s1 = h1u + ((size_t)(0*NBGS + qb*4))*16384;  // h1(0,bg0)
      #pragma unroll
      for (int j = 0; j < 4; ++j){
        int c = wv*4 + j;
        __builtin_amdgcn_global_load_lds((GU32*)(s1 + (size_t)(c*64 + lane)*8),
                                         (LU32*)(smem + c*1024), 16, 0, 0x11);
      }
    }
    if (wv == 8) poll_deps(f1d + (qb*4+1)*16, f2d + (qb*4+1)*32, lane, 1u, 0u);
    BAR();

    // ---- main loop: bodies 4..8191 (+1 service body) ----
    #pragma clang loop unroll(disable)
    for (int i = 4; i <= NBODY; ++i){
      const bool m_ = (i < NBODY);
      const int t = i>>2, b = i&3, bg = qb*4 + b;
      float yv = 0.f;
      if (wrk){
        if (m_) yv = yT[t*128 + bg*16 + l15];          // issued first: retired by WAITV4
        if (i+1 <= NBODY-1){
          int t1 = (i+1)>>2, bg1 = qb*4 + ((i+1)&3);
          const unsigned short* s1 = h1u + ((size_t)((((t1-1)&3))*NBGS + bg1))*16384;
          unsigned char* d = smem + ((i+1)&1)*32768;
          #pragma unroll
          for (int j = 0; j < 4; ++j){
            int c = wv*4 + j;
            __builtin_amdgcn_global_load_lds((GU32*)(s1 + (size_t)(c*64 + lane)*8),
                                             (LU32*)(d + c*1024), 16, 0, 0x11);
          }
          WAITV4();                                    // retires stage(i) + yv only
        } else {
          WAITV0();
        }
      } else {
        // service wave: issue stores for body i-1 (bnc stable since B_bounce(i-1))
        int ip = i-1, tp = ip>>2, bp = qb*4 + (ip&3);
        unsigned short* sb = h1u + ((size_t)((tp&3)*NBGS + bp))*16384;
        #pragma unroll
        for (int q = 0; q < 2; ++q){
          int pc = lane + q*64;
          int pl = pc>>6, idx = pc&63, kb = idx>>4, n = idx&15;
          ushort8 v = *(const ushort8*)(bnc + pl*512 + idx*8);
          st128cc(sb + pl*8192 + ((ug*4 + kb)*16 + n)*8, v);
        }
      }
      BAR();                                           // B_e: tile(i) ready, bnc free
      if (wrk){
        if (m_){
          f32x4 acc = matvec(smem + (i&1)*32768, whi, wlo, hig, l15);
          float gi = acc[0] + bsum[0] + wih[0]*yv;
          float gf = acc[1] + bsum[1] + wih[1]*yv;
          float gg = acc[2] + bsum[2] + wih[2]*yv;
          float go = acc[3] + bsum[3] + wih[3]*yv;
          float* cp = cst + ((ul*16 + l15)*4 + b);
          float cn = sigm(gf)*(*cp) + sigm(gi)*tanhf_fast(gg);
          *cp = cn;
          float hn = sigm(go)*tanhf_fast(cn);
          unsigned short hb = f2bf(hn);
          bnc[(k8l*16 + l15)*8 + kk]       = hb;
          bnc[512 + (k8l*16 + l15)*8 + kk] = f2bf(hn - bf2f(hb));
          WAITL0();
        }
      } else {
        if (i+2 <= NBODY-1){
          int tj = (i+2)>>2, bgj = qb*4 + ((i+2)&3);
          poll_deps(f1d + bgj*16, f2d + bgj*32, lane,
                    (unsigned)tj, (tj>=4)?(unsigned)(tj-3):0u);   // implicit drain of stores
        } else {
          WAITV0();
        }
        if (lane == 0){                                // publish body i-1 (stores drained)
          int ip = i-1, tp = ip>>2, bp = qb*4 + (ip&3);
          fstore(f1d + bp*16 + ug, (unsigned)(tp+1));
        }
      }
      BAR();                                           // B_bounce
    }
  } else {
    // ========== layer 2 (+fused out on j0): 2 quads x 32 blocks, 16 units ==========
    const int b2 = blk - 32, qb = b2 >> 5, j32 = b2 & 31;
    const int u0 = j32*16;
    const int g  = wv >> 2;          // workers: 0 = hh2(+act), 1 = ih2(+psum,+out on j0)
    const int mt = wv & 3;
    const int ul = mt*4 + hig;
    short8 whi[16], wlo[16];
    float bsum[4];
    if (wrk){
      apack((g==0) ? Whh2 : Wih2, u0 + mt*4, l15, hig, whi, wlo);
      #pragma unroll
      for (int r = 0; r < 4; ++r) bsum[r] = bi2[r*HID + u0 + ul] + bh2[r*HID + u0 + ul];
    }
    const int k8l = ul>>3, kk = ul&7;
    const float bl = blin[0];
    float* lwl  = (float*)(smem + LWLB);
    float* outp = (float*)(smem + OUTPB);

    for (int r = tid; r < 1024; r += 576) cst[r] = 0.f;
    if (j32 == 0 && tid < 512) lwl[tid] = Wlin[tid];
    // warmup: deps(0), stage(0), deps(1)
    if (wv == 8) poll_deps(f1d + (qb*4+0)*16, f2d + (qb*4+0)*32, lane, 1u, 0u);
    WAITL0(); BAR();
    if (wrk){
      const unsigned short* s2 = h2u + ((size_t)(3*NBGS + qb*4))*16384;   // h2(-1,bg0)=0
      const unsigned short* s1 = h1u + ((size_t)(0*NBGS + qb*4))*16384;   // h1(0,bg0)
      #pragma unroll
      for (int j = 0; j < 4; ++j){
        int c = wv*4 + j;
        __builtin_amdgcn_global_load_lds((GU32*)(s2 + (size_t)(c*64 + lane)*8),
                                         (LU32*)(smem + c*1024), 16, 0, 0x11);
        __builtin_amdgcn_global_load_lds((GU32*)(s1 + (size_t)(c*64 + lane)*8),
                                         (LU32*)(smem + 32768 + c*1024), 16, 0, 0x11);
      }
    }
    if (wv == 8) poll_deps(f1d + (qb*4+1)*16, f2d + (qb*4+1)*32, lane, 1u, 0u);
    BAR();

    // ---- main loop: bodies 0..8191 (+1 service body) ----
    #pragma clang loop unroll(disable)
    for (int i = 0; i <= NBODY; ++i){
      const bool m_ = (i < NBODY);
      const int t = i>>2, b = i&3, bg = qb*4 + b;
      if (wrk){
        if (i+1 <= NBODY-1){
          int t1 = (i+1)>>2, bg1 = qb*4 + ((i+1)&3);
          const unsigned short* s2 = h2u + ((size_t)((((t1+3)&3))*NBGS + bg1))*16384;
          const unsigned short* s1 = h1u + ((size_t)(((t1&3))*NBGS + bg1))*16384;
          unsigned char* d = smem + ((i+1)&1)*65536;
          #pragma unroll
          for (int j = 0; j < 4; ++j){
            int c = wv*4 + j;
            __builtin_amdgcn_global_load_lds((GU32*)(s2 + (size_t)(c*64 + lane)*8),
                                             (LU32*)(d + c*1024), 16, 0, 0x11);
            __builtin_amdgcn_global_load_lds((GU32*)(s1 + (size_t)(c*64 + lane)*8),
                                             (LU32*)(d + 32768 + c*1024), 16, 0, 0x11);
          }
          WAITV8();                                    // retires stage(i) only
        } else {
          WAITV0();
        }
      } else if (i >= 1){
        int ip = i-1, tp = ip>>2, bp = qb*4 + (ip&3);
        unsigned short* sb = h2u + ((size_t)((tp&3)*NBGS + bp))*16384;
        int pl = lane>>5, idx = lane&31, kb = idx>>4, n = idx&15;
        ushort8 v = *(const ushort8*)(bnc + pl*256 + idx*8);
        st128cc(sb + pl*8192 + ((j32*2 + kb)*16 + n)*8, v);
      }
      BAR();                                           // B_e
      f32x4 acc = (f32x4){0.f,0.f,0.f,0.f};
      if (wrk){
        if (m_){
          const unsigned char* tb = smem + (i&1)*65536 + (g ? 32768 : 0);
          acc = matvec(tb, whi, wlo, hig, l15);
          if (g == 1) *(f32x4*)(smem + PSUMB + (unsigned)(mt*64 + lane)*16u) = acc;
          if (g == 1 && j32 == 0 && t >= 1){
            const unsigned char* t2 = smem + (i&1)*65536;   // h2(t-1,bg)
            int s = mt*4 + hig;
            float a = 0.f;
            #pragma unroll
            for (int k8r = 0; k8r < 4; ++k8r){
              int k8 = s*4 + k8r;
              unsigned eb = (unsigned)(k8*16 + l15)*16u;
              ushort8 h8 = *(const ushort8*)(t2 + eb);
              ushort8 l8 = *(const ushort8*)(t2 + 16384u + eb);
              #pragma unroll
              for (int c = 0; c < 8; ++c)
                a += (bf2f(h8[c]) + bf2f(l8[c])) * lwl[k8*8 + c];
            }
            outp[s*16 + l15] = a;
          }
          WAITL0();
        }
      } else {
        if (i+2 <= NBODY-1){
          int tj = (i+2)>>2, bgj = qb*4 + ((i+2)&3);
          poll_deps(f1d + bgj*16, f2d + bgj*32, lane, (unsigned)(tj+1), (unsigned)tj);
        } else {
          WAITV0();
        }
        if (i >= 1 && lane == 0){
          int ip = i-1, tp = ip>>2, bp = qb*4 + (ip&3);
          fstore(f2d + bp*32 + j32, (unsigned)(tp+1));
        }
      }
      BAR();                                           // B_g: psum/outp ready
      if (wrk && m_){
        if (g == 0){
          f32x4 ps = *(const f32x4*)(smem + PSUMB + (unsigned)(mt*64 + lane)*16u);
          float gi = acc[0] + ps[0] + bsum[0];
          float gf = acc[1] + ps[1] + bsum[1];
          float gg = acc[2] + ps[2] + bsum[2];
          float go = acc[3] + ps[3] + bsum[3];
          float* cp = cst + ((ul*16 + l15)*4 + b);
          float cn = sigm(gf)*(*cp) + sigm(gi)*tanhf_fast(gg);
          *cp = cn;
          float hn = sigm(go)*tanhf_fast(cn);
          unsigned short hb = f2bf(hn);
          bnc[(k8l*16 + l15)*8 + kk]       = hb;
          bnc[256 + (k8l*16 + l15)*8 + kk] = f2bf(hn - bf2f(hb));
        }
        if (wv == 4 && j32 == 0 && t >= 1 && lane < 16){
          float s = bl;
          #pragma unroll
          for (int r = 0; r < 16; ++r) s += outp[r*16 + lane];
          out[((size_t)(bg*16 + lane))*LSEQ + (t-1)] = s;   // counted in wv4 ledger, retires next body
        }
        WAITL0();
      }
      BAR();                                           // B_g2: bounce ready
    }
    // epilogue: out(2047) on j0 blocks, 4 rounds
    if (j32 == 0){
      for (int b = 0; b < 4; ++b){
        const int bg = qb*4 + b;
        if (wv == 8) poll_deps(f1d + bg*16, f2d + bg*32, lane, 0u, 2048u);
        BAR();
        if (wrk){
          const unsigned short* s2 = h2u + ((size_t)(3*NBGS + bg))*16384;  // h2(2047): slot 3
          #pragma unroll
          for (int j = 0; j < 4; ++j){
            int c = wv*4 + j;
            __builtin_amdgcn_global_load_lds((GU32*)(s2 + (size_t)(c*64 + lane)*8),
                                             (LU32*)(smem + c*1024), 16, 0, 0x11);
          }
          WAITV0();
        }
        BAR();
        if (wrk && g == 1){
          int s = mt*4 + hig;
          float a = 0.f;
          #pragma unroll
          for (int k8r = 0; k8r < 4; ++k8r){
            int k8 = s*4 + k8r;
            unsigned eb = (unsigned)(k8*16 + l15)*16u;
            ushort8 h8 = *(const ushort8*)(smem + eb);
            ushort8 l8 = *(const ushort8*)(smem + 16384u + eb);
            #pragma unroll
            for (int c = 0; c < 8; ++c)
              a += (bf2f(h8[c]) + bf2f(l8[c])) * lwl[k8*8 + c];
          }
          outp[s*16 + l15] = a;
          WAITL0();
        }
        BAR();
        if (wrk && wv == 4 && lane < 16){
          float s = bl;
          #pragma unroll
          for (int r = 0; r < 16; ++r) s += outp[r*16 + lane];
          out[((size_t)(bg*16 + lane))*LSEQ + 2047] = s;
        }
      }
    }
  }
}

extern "C" void kernel_launch(void* const* d_in, const int* in_sizes, int n_in,
                              void* d_out, int out_size, void* d_ws, size_t ws_size,
                              hipStream_t stream){
  (void)in_sizes; (void)n_in; (void)out_size; (void)ws_size;
  const float* y    = (const float*)d_in[0];
  const float* Wih1 = (const float*)d_in[1];
  const float* Whh1 = (const float*)d_in[2];
  const float* bi1  = (const float*)d_in[3];
  const float* bh1  = (const float*)d_in[4];
  const float* Wih2 = (const float*)d_in[5];
  const float* Whh2 = (const float*)d_in[6];
  const float* bi2  = (const float*)d_in[7];
  const float* bh2  = (const float*)d_in[8];
  const float* Wlin = (const float*)d_in[9];
  const float* blin = (const float*)d_in[10];
  float* ws  = (float*)d_ws;
  float* out = (float*)d_out;

  hipLaunchKernelGGL(init_kernel, dim3(1024), dim3(256), 0, stream, y, ws);

  const float* yT = ws + OFF_YT;
  unsigned short* h1u = (unsigned short*)(ws + OFF_H1);
  unsigned short* h2u = (unsigned short*)(ws + OFF_H2);
  unsigned* f1d = (unsigned*)(ws + OFF_F1);
  unsigned* f2d = (unsigned*)(ws + OFF_F2);

  void* args[] = { (void*)&yT, (void*)&Wih1, (void*)&Whh1, (void*)&bi1, (void*)&bh1,
                   (void*)&Wih2, (void*)&Whh2, (void*)&bi2, (void*)&bh2,
                   (void*)&Wlin, (void*)&blin, (void*)&h1u, (void*)&h2u,
                   (void*)&out, (void*)&f1d, (void*)&f2d };
  hipLaunchCooperativeKernel((void*)lstm_kernel, dim3(96), dim3(576), args, 0, stream);
}